// Round 10
// baseline (485.659 us; speedup 1.0000x reference)
//
#include <hip/hip_runtime.h>
#include <math.h>

#define KSIZE 7
#define C_CH  256
#define HW    256
#define BATCH 8

#define TH    32            // output rows per tile
#define ROWS  (TH + 6)      // 38 input rows staged (3-row halo each side)
#define NQ    (ROWS * 66)   // staged quads/tile: 66 per row (zero|64 data|zero)
#define NT    (HW / TH)     // 8 tiles per (n,c) plane

// ---------------------------------------------------------------------------
// Kernel 1: synthesize the 256 x 7 x 7 Gabor filter bank into d_ws.
// ---------------------------------------------------------------------------
__global__ void gabor_weights_kernel(const float* __restrict__ log_sigma,
                                     const float* __restrict__ log_freq,
                                     const float* __restrict__ theta,
                                     float* __restrict__ gw) {
    int c = threadIdx.x;
    if (c >= C_CH) return;
    float sigma = expf(log_sigma[c]);
    float freq  = expf(log_freq[c]);
    float ct = cosf(theta[c]);
    float st = sinf(theta[c]);
    float inv_sigma = 1.0f / sigma;
    float vals[KSIZE * KSIZE];
    float sum = 0.0f;
    #pragma unroll
    for (int i = 0; i < KSIZE; ++i) {
        #pragma unroll
        for (int j = 0; j < KSIZE; ++j) {
            float dx = (float)(i - 3);
            float dy = (float)(j - 3);
            float x0 = (dx * ct + dy * st) * inv_sigma;
            float x1 = (-dx * st + dy * ct) * inv_sigma;
            float g  = expf(-0.5f * (x0 * x0 + x1 * x1));
            float v  = g * cosf(6.283185307179586f * freq * x0);
            vals[i * KSIZE + j] = v;
            sum += v;
        }
    }
    float inv = 1.0f / sum;
    #pragma unroll
    for (int k = 0; k < KSIZE * KSIZE; ++k)
        gw[c * (KSIZE * KSIZE) + k] = vals[k] * inv;
}

// ---------------------------------------------------------------------------
// Kernel 2: depthwise 7x7 conv; PRODUCER/CONSUMER WAVE SPECIALIZATION.
// 512 threads/block, one block per (n,c) plane, 8 tiles streamed with
// double-buffered LDS.  Waves 0-3 (tid<256) ONLY stage: 10 global float4
// loads issued back-to-back, then 40 ds_write_b32 deinterleaved into 4
// dword segments (seg[s][row][k] = padded col 4k+s) -> consumer reads are
// per-lane stride 4B, conflict-free (R9: conflicts 6.3e7 -> 2.3e6).
// Waves 4-7 ONLY compute: zero global loads in their stream, so no vmcnt
// wait can ever couple them to staging; their stores are fire-and-forget.
// Producer vmcnt(0) stalls sit in producer waves only -- the SIMDs keep
// issuing consumer FMAs, so HBM streams continuously (breaks the global
// stage/compute phase-lock of R1-R9).  Raw s_barrier + role-local waits.
// ---------------------------------------------------------------------------
__global__ __launch_bounds__(512, 4)
void gabor_conv_kernel(const float* __restrict__ x,
                       const float* __restrict__ gw,
                       float* __restrict__ out) {
    __shared__ float seg[2][4][ROWS][66];   // 2 x 39,936 B = 79,872 B

    const int tid = threadIdx.x;
    const int c   = blockIdx.x;
    const int n   = blockIdx.y;
    const bool producer = tid < 256;

    const size_t plane = ((size_t)n * C_CH + c) * (size_t)(HW * HW);
    const float* xp = x + plane;
    float*       op = out + plane;

    // ---- consumer-side setup
    const int tid2 = tid - 256;
    const int lane = tid2 & 63;    // output cols 4*lane..4*lane+3
    const int wv   = tid2 >> 6;    // tile rows 8*wv..8*wv+7
    const int ob   = wv * 8;
    float w[KSIZE * KSIZE];
    if (!producer) {
        const float* wp = gw + c * (KSIZE * KSIZE);
        #pragma unroll
        for (int k = 0; k < KSIZE * KSIZE; ++k) w[k] = wp[k];
    }

    // ---- producer staging: tile T -> seg[buf]; 10 loads then 40 ds_writes
#define STAGE(BUF, T) do {                                                    \
        const int row0_ = (T) * TH - 3;                                       \
        float4 v[10];                                                         \
        _Pragma("unroll")                                                     \
        for (int u = 0; u < 10; ++u) {                                        \
            const int idx = tid + u * 256;                                    \
            v[u] = make_float4(0.f, 0.f, 0.f, 0.f);                           \
            if (idx < NQ) {                                                   \
                const int rr = idx / 66;                                      \
                const int q  = idx - rr * 66;                                 \
                const int gr = row0_ + rr;                                    \
                if (q >= 1 && q <= 64 && gr >= 0 && gr < HW)                  \
                    v[u] = *reinterpret_cast<const float4*>(                  \
                               xp + (size_t)gr * HW + (q - 1) * 4);           \
            }                                                                 \
        }                                                                     \
        _Pragma("unroll")                                                     \
        for (int u = 0; u < 10; ++u) {                                        \
            const int idx = tid + u * 256;                                    \
            if (idx < NQ) {                                                   \
                const int rr = idx / 66;                                      \
                const int q  = idx - rr * 66;                                 \
                seg[BUF][0][rr][q] = v[u].x;                                  \
                seg[BUF][1][rr][q] = v[u].y;                                  \
                seg[BUF][2][rr][q] = v[u].z;                                  \
                seg[BUF][3][rr][q] = v[u].w;                                  \
            }                                                                 \
        }                                                                     \
    } while (0)

    // ---- prologue: stage tile 0 into buffer 0
    if (producer) {
        STAGE(0, 0);
        asm volatile("s_waitcnt vmcnt(0)" ::: "memory");
    }
    asm volatile("s_waitcnt lgkmcnt(0)" ::: "memory");
    asm volatile("s_barrier" ::: "memory");

    for (int t = 0; t < NT; ++t) {
        const int cur = t & 1;
        if (producer) {
            if (t + 1 < NT) STAGE(cur ^ 1, t + 1);
            asm volatile("s_waitcnt vmcnt(0)" ::: "memory");
        } else {
            // ---- compute 8 rows x 4 cols from seg[cur] (stride-4B reads)
            float acc[8][4];
            #pragma unroll
            for (int o = 0; o < 8; ++o)
                #pragma unroll
                for (int cc = 0; cc < 4; ++cc) acc[o][cc] = 0.f;

            #pragma unroll
            for (int r = 0; r < 14; ++r) {
                const int rw = ob + r;
                float f[11];
                #pragma unroll
                for (int m = 1; m <= 10; ++m)
                    f[m] = seg[cur][m & 3][rw][lane + (m >> 2)];
                #pragma unroll
                for (int o = 0; o < 8; ++o) {
                    if (o <= r && r <= o + 6) {   // compile-time after unroll
                        const int ki = r - o;
                        #pragma unroll
                        for (int cc = 0; cc < 4; ++cc) {
                            #pragma unroll
                            for (int j = 0; j < KSIZE; ++j)
                                acc[o][cc] += f[cc + j + 1] * w[ki * KSIZE + j];
                        }
                    }
                }
            }

            // ---- stores: fire-and-forget (no vmcnt wait in this stream)
            const int orow0 = t * TH + ob;
            #pragma unroll
            for (int o = 0; o < 8; ++o) {
                float4 vv = make_float4(acc[o][0], acc[o][1], acc[o][2], acc[o][3]);
                *reinterpret_cast<float4*>(op + (size_t)(orow0 + o) * HW + lane * 4) = vv;
            }
        }
        asm volatile("s_waitcnt lgkmcnt(0)" ::: "memory");
        asm volatile("s_barrier" ::: "memory");
    }
#undef STAGE
}

extern "C" void kernel_launch(void* const* d_in, const int* in_sizes, int n_in,
                              void* d_out, int out_size, void* d_ws, size_t ws_size,
                              hipStream_t stream) {
    const float* x  = (const float*)d_in[0];
    const float* ls = (const float*)d_in[1];
    const float* lf = (const float*)d_in[2];
    const float* th = (const float*)d_in[3];
    float* out = (float*)d_out;
    float* gw  = (float*)d_ws;   // 256*49*4 = 50176 bytes of scratch

    gabor_weights_kernel<<<1, 256, 0, stream>>>(ls, lf, th, gw);

    dim3 grid(C_CH, BATCH);      // one block per (n,c) plane
    gabor_conv_kernel<<<grid, 512, 0, stream>>>(x, gw, out);
}